// Round 13
// baseline (648.226 us; speedup 1.0000x reference)
//
#include <hip/hip_runtime.h>
#include <hip/hip_bf16.h>

#define KN  2048   // nodes
#define KD  256    // emb dim = HF
#define KH  4      // heads
#define KF  64     // feat/head
#define KT  64     // time steps
#define NCS 32     // colsum partial buffers
#define MAXE 256
#define NBLK 768   // grid size: 3 blocks/CU needed, capacity 4 (launch_bounds 256,4)

typedef __attribute__((ext_vector_type(8))) short short8;
typedef __attribute__((ext_vector_type(4))) float floatx4;

// ---------------- helpers ----------------
__device__ __forceinline__ float wave_sum(float v) {
    #pragma unroll
    for (int o = 32; o > 0; o >>= 1) v += __shfl_xor(v, o, 64);
    return v;
}
__device__ __forceinline__ float wave_max(float v) {
    #pragma unroll
    for (int o = 32; o > 0; o >>= 1) v = fmaxf(v, __shfl_xor(v, o, 64));
    return v;
}
__device__ __forceinline__ short f2bs(float x) {
    union { __hip_bfloat16 h; short s; } u;
    u.h = __float2bfloat16(x);
    return u.s;
}

// device-scope soft grid barrier: counter per barrier, zeroed by host memset.
// All NBLK blocks are co-resident (capacity 4 blocks/CU, grid needs 3).
__device__ __forceinline__ void soft_sync(unsigned* bar, int idx) {
    __syncthreads();
    if (threadIdx.x == 0) {
        __threadfence();                         // release all prior writes
        atomicAdd(&bar[idx], 1u);
        while (atomicAdd(&bar[idx], 0u) < (unsigned)NBLK)
            __builtin_amdgcn_s_sleep(8);
        __threadfence();                         // acquire
    }
    __syncthreads();
}

struct MegaArgs {
    const float *y, *adj, *emb;
    const float *pos_w, *neg_w, *pos_pw, *neg_pw, *self_w;
    const float *pos_pb, *neg_pb, *self_b;
    const float *pos_wu, *pos_wv, *neg_wu, *neg_wv;
    const float *pos_b, *neg_b;
    const float *mlp_pos_w, *mlp_pos_b, *mlp_neg_w, *mlp_neg_b;
    const float *sem_w1, *sem_b1, *sem_w2;
    float *ycs; unsigned char *cd;
    float *S_pos, *S_neg, *P_pos, *P_neg, *sup, *psup, *nsup;
    float *G_pos, *G_neg, *T0, *T1, *T2, *X, *colsum;
    float *f1p, *f2p, *f1n, *f2n;
    unsigned *bar;
    float *out;
};

// ---------------- corr body: upper-tri 64x64 tile, writes (i,j) AND (j,i) --
__device__ __forceinline__ void corr_body(const float* __restrict__ ycs,
                                          const float* __restrict__ adj,
                                          unsigned char* __restrict__ code,
                                          int blk, char* smem) {
    float (*As)[68] = (float(*)[68])smem;            // 16x68 f32
    float (*Bs)[68] = (float(*)[68])(smem + 4352);
    int bi = 0, rem = blk;
    while (rem >= 32 - bi) { rem -= 32 - bi; bi++; }
    int bj = bi + rem;
    int i0 = bi * 64, j0 = bj * 64;
    int t = threadIdx.x;
    int tx = t & 15, ty = t >> 4;
    int ar = t >> 2, ac = (t & 3) * 4;
    float acc[4][4] = {};
    for (int kt = 0; kt < KT; kt += 16) {
        float4 a4 = *reinterpret_cast<const float4*>(&ycs[(size_t)(i0 + ar) * KT + kt + ac]);
        float4 b4 = *reinterpret_cast<const float4*>(&ycs[(size_t)(j0 + ar) * KT + kt + ac]);
        As[ac + 0][ar] = a4.x; As[ac + 1][ar] = a4.y; As[ac + 2][ar] = a4.z; As[ac + 3][ar] = a4.w;
        Bs[ac + 0][ar] = b4.x; Bs[ac + 1][ar] = b4.y; Bs[ac + 2][ar] = b4.z; Bs[ac + 3][ar] = b4.w;
        __syncthreads();
        #pragma unroll
        for (int kk = 0; kk < 16; kk++) {
            float4 av = *reinterpret_cast<const float4*>(&As[kk][ty * 4]);
            float4 bv = *reinterpret_cast<const float4*>(&Bs[kk][tx * 4]);
            float a4v[4] = {av.x, av.y, av.z, av.w};
            float b4v[4] = {bv.x, bv.y, bv.z, bv.w};
            #pragma unroll
            for (int ii = 0; ii < 4; ii++)
                #pragma unroll
                for (int jj = 0; jj < 4; jj++) acc[ii][jj] += a4v[ii] * b4v[jj];
        }
        __syncthreads();
    }
    #pragma unroll
    for (int ii = 0; ii < 4; ii++) {
        int i = i0 + ty * 4 + ii;
        int jb = j0 + tx * 4;
        float4 av4 = *reinterpret_cast<const float4*>(&adj[(size_t)i * KN + jb]);
        float a4v[4] = {av4.x, av4.y, av4.z, av4.w};
        uchar4 cc;
        unsigned char* c = (unsigned char*)&cc;
        #pragma unroll
        for (int jj = 0; jj < 4; jj++)
            c[jj] = (a4v[jj] != 0.0f) ? ((acc[ii][jj] >= 0.1f) ? 1 : 2) : 0;
        *reinterpret_cast<uchar4*>(&code[(size_t)i * KN + jb]) = cc;
    }
    if (bi != bj) {
        #pragma unroll
        for (int jj = 0; jj < 4; jj++) {
            int j = j0 + tx * 4 + jj;
            int ib = i0 + ty * 4;
            float4 av4 = *reinterpret_cast<const float4*>(&adj[(size_t)j * KN + ib]);
            float a4v[4] = {av4.x, av4.y, av4.z, av4.w};
            uchar4 cc;
            unsigned char* c = (unsigned char*)&cc;
            #pragma unroll
            for (int ii = 0; ii < 4; ii++)
                c[ii] = (a4v[ii] != 0.0f) ? ((acc[ii][jj] >= 0.1f) ? 1 : 2) : 0;
            *reinterpret_cast<uchar4*>(&code[(size_t)j * KN + ib]) = cc;
        }
    }
}

// ---------------- MFMA bf16 GEMM body: 64x64 C tile, K=256 ----------------
template <bool TANH>
__device__ __forceinline__ void mfma_gemm_body(
    const float* __restrict__ A, int lda, int bm,
    const float* __restrict__ B, int ldb, int bn,
    const float* __restrict__ bias,
    float* __restrict__ C, int ldc, int cn,
    float* __restrict__ f1h, float* __restrict__ f2h,
    const float* __restrict__ wu_h, const float* __restrict__ wv_h,
    char* smem)
{
    short* As = (short*)smem;            // [64][40] bf16 (row m, col k)
    short* Bs = (short*)(smem + 5120);   // [64][40] bf16 (row n, col k)
    int t = threadIdx.x;
    int w = t >> 6, lane = t & 63;
    int m16 = lane & 15, kq = lane >> 4;
    floatx4 acc0 = {0,0,0,0}, acc1 = {0,0,0,0}, acc2 = {0,0,0,0}, acc3 = {0,0,0,0};
    int ar = t >> 2, acq = (t & 3) * 8;
    int bnn = t & 63, bkg = (t >> 6) * 8;
    for (int kt = 0; kt < KD; kt += 32) {
        const float* pa = &A[(size_t)(bm + ar) * lda + kt + acq];
        float4 a0 = *(const float4*)pa;
        float4 a1 = *(const float4*)(pa + 4);
        short8 av;
        av[0] = f2bs(a0.x); av[1] = f2bs(a0.y); av[2] = f2bs(a0.z); av[3] = f2bs(a0.w);
        av[4] = f2bs(a1.x); av[5] = f2bs(a1.y); av[6] = f2bs(a1.z); av[7] = f2bs(a1.w);
        const float* pb = &B[(size_t)(kt + bkg) * ldb + bn + bnn];
        short8 bv;
        #pragma unroll
        for (int u = 0; u < 8; u++) bv[u] = f2bs(pb[(size_t)u * ldb]);
        __syncthreads();   // previous iteration's frag reads complete
        *(short8*)&As[ar * 40 + acq] = av;
        *(short8*)&Bs[bnn * 40 + bkg] = bv;
        __syncthreads();
        short8 af  = *(short8*)&As[(w * 16 + m16) * 40 + kq * 8];
        short8 bf0 = *(short8*)&Bs[( 0 + m16) * 40 + kq * 8];
        short8 bf1 = *(short8*)&Bs[(16 + m16) * 40 + kq * 8];
        short8 bf2 = *(short8*)&Bs[(32 + m16) * 40 + kq * 8];
        short8 bf3 = *(short8*)&Bs[(48 + m16) * 40 + kq * 8];
        acc0 = __builtin_amdgcn_mfma_f32_16x16x32_bf16(af, bf0, acc0, 0, 0, 0);
        acc1 = __builtin_amdgcn_mfma_f32_16x16x32_bf16(af, bf1, acc1, 0, 0, 0);
        acc2 = __builtin_amdgcn_mfma_f32_16x16x32_bf16(af, bf2, acc2, 0, 0, 0);
        acc3 = __builtin_amdgcn_mfma_f32_16x16x32_bf16(af, bf3, acc3, 0, 0, 0);
    }
    int row0 = bm + w * 16 + kq * 4;
    floatx4 accs[4] = {acc0, acc1, acc2, acc3};
    #pragma unroll
    for (int nb = 0; nb < 4; nb++) {
        #pragma unroll
        for (int r = 0; r < 4; r++) {
            int col = nb * 16 + m16;
            float v = accs[nb][r] + (bias ? bias[col] : 0.0f);
            if (TANH) {
                float vc = fminf(fmaxf(v, -9.0f), 9.0f);
                float ex = __expf(2.0f * vc);
                v = (ex - 1.0f) / (ex + 1.0f);
            }
            C[(size_t)(row0 + r) * ldc + cn + col] = v;
        }
    }
    if (f1h) {
        float wuv[4], wvv[4];
        #pragma unroll
        for (int nb = 0; nb < 4; nb++) { wuv[nb] = wu_h[nb * 16 + m16]; wvv[nb] = wv_h[nb * 16 + m16]; }
        #pragma unroll
        for (int r = 0; r < 4; r++) {
            float p1 = accs[0][r] * wuv[0] + accs[1][r] * wuv[1] + accs[2][r] * wuv[2] + accs[3][r] * wuv[3];
            float p2 = accs[0][r] * wvv[0] + accs[1][r] * wvv[1] + accs[2][r] * wvv[2] + accs[3][r] * wvv[3];
            #pragma unroll
            for (int o = 1; o < 16; o <<= 1) {
                p1 += __shfl_xor(p1, o, 64);
                p2 += __shfl_xor(p2, o, 64);
            }
            if (m16 == 0) { f1h[row0 + r] = p1; f2h[row0 + r] = p2; }
        }
    }
}

// ------ attn body: single scan -> both rels, wave=head (round-11-proven) ---
__device__ __forceinline__ void attn_body(const MegaArgs& a, int i, char* smem) {
    int* jlp = (int*)smem;                  // [256]
    int* jln = (int*)(smem + 1024);         // [256]
    float* lg = (float*)(smem + 2048);      // [2][KH][256]
    int* cnts = (int*)(smem + 10240);       // [2]
    int w = threadIdx.x >> 6, lane = threadIdx.x & 63;
    if (threadIdx.x == 0) { cnts[0] = 0; cnts[1] = 0; }
    __syncthreads();
    unsigned long long lmask = (1ull << lane) - 1ull;
    #pragma unroll
    for (int it = 0; it < 2; it++) {
        int base = w * 512 + it * 256;
        uchar4 cv = *reinterpret_cast<const uchar4*>(&a.cd[(size_t)i * KN + base + lane * 4]);
        const unsigned char* ce = (const unsigned char*)&cv;
        #pragma unroll
        for (int e = 0; e < 4; e++) {
            bool ip = (ce[e] == (unsigned char)1);
            bool in_ = (ce[e] == (unsigned char)2);
            unsigned long long balp = __ballot(ip);
            unsigned long long baln = __ballot(in_);
            int tp = __popcll(balp), tn = __popcll(baln);
            int basep = 0, basen = 0;
            if (lane == 0) {
                if (tp) basep = atomicAdd(&cnts[0], tp);
                if (tn) basen = atomicAdd(&cnts[1], tn);
            }
            basep = __shfl(basep, 0, 64);
            basen = __shfl(basen, 0, 64);
            int j = base + lane * 4 + e;
            if (ip) { int idx = basep + __popcll(balp & lmask); if (idx < MAXE) jlp[idx] = j; }
            if (in_) { int idx = basen + __popcll(baln & lmask); if (idx < MAXE) jln[idx] = j; }
        }
    }
    __syncthreads();
    int cp = cnts[0]; if (cp > MAXE) cp = MAXE;
    int cn2 = cnts[1]; if (cn2 > MAXE) cn2 = MAXE;
    int cpR = (cp + 3) & ~3, cnR = (cn2 + 3) & ~3;
    if (threadIdx.x < cpR - cp) jlp[cp + threadIdx.x] = 0;
    if (threadIdx.x < cnR - cn2) jln[cn2 + threadIdx.x] = 0;
    __syncthreads();
    int h = w;
    int g = lane >> 4, q4 = (lane & 15) * 4;
    #pragma unroll
    for (int rel = 0; rel < 2; rel++) {
        const int* jl = rel ? jln : jlp;
        int count = rel ? cn2 : cp;
        int countR = rel ? cnR : cpR;
        const float* f1 = rel ? a.f1n : a.f1p;
        const float* f2 = rel ? a.f2n : a.f2p;
        const float* S  = rel ? a.S_neg : a.S_pos;
        const float* P  = rel ? a.P_neg : a.P_pos;
        const float* b  = rel ? a.neg_b : a.pos_b;
        float* G        = rel ? a.G_neg : a.G_pos;
        float* lgr = lg + (rel * KH + h) * MAXE;
        float f2i = f2[h * KN + i];
        float m = -1e30f;
        for (int k = lane; k < count; k += 64) {
            float x = f1[h * KN + jl[k]] + f2i;
            x = (x > 0.0f) ? x : 0.2f * x;          // leaky_relu 0.2
            lgr[k] = x;
            m = fmaxf(m, x);
        }
        m = wave_max(m);
        float ps = 0.0f;
        for (int k = lane; k < count; k += 64) {
            float e = __expf(lgr[k] - m);
            lgr[k] = e;
            ps += e;
        }
        float denom = wave_sum(ps);
        for (int k2 = count + lane; k2 < countR; k2 += 64) lgr[k2] = 0.0f;
        const float* Sh4 = S + h * KF + q4;
        float ax = 0.0f, ay = 0.0f, az = 0.0f, aw = 0.0f;
        for (int k = 0; k < countR; k += 4) {
            int j = jl[k + g];
            float wgt = lgr[k + g];
            float4 sv = *reinterpret_cast<const float4*>(&Sh4[(size_t)j * KD]);
            ax += wgt * sv.x; ay += wgt * sv.y; az += wgt * sv.z; aw += wgt * sv.w;
        }
        #pragma unroll
        for (int o = 16; o < 64; o <<= 1) {
            ax += __shfl_xor(ax, o, 64); ay += __shfl_xor(ay, o, 64);
            az += __shfl_xor(az, o, 64); aw += __shfl_xor(aw, o, 64);
        }
        if (g == 0) {
            float inv = count ? (1.0f / denom) : 0.0f;
            int col = h * KF + q4;
            size_t idx = (size_t)i * KD + col;
            float4 pv = *reinterpret_cast<const float4*>(&P[idx]);
            float4 o4;
            o4.x = ax * inv + b[col + 0] + pv.x;
            o4.y = ay * inv + b[col + 1] + pv.y;
            o4.z = az * inv + b[col + 2] + pv.z;
            o4.w = aw * inv + b[col + 3] + pv.w;
            *reinterpret_cast<float4*>(&G[idx]) = o4;
        }
    }
}

// ---------------- combine body ----------------
__device__ __forceinline__ void combine_body(const MegaArgs& a, int n, char* smem) {
    float* sbuf = (float*)smem;   // [4][3]
    int d = threadIdx.x;
    size_t idx = (size_t)n * KD + d;
    float w2d = a.sem_w2[d];
    float p0 = a.T0[idx] * w2d, p1 = a.T1[idx] * w2d, p2 = a.T2[idx] * w2d;
    int wv = d >> 6, lane = d & 63;
    float s0 = wave_sum(p0), s1 = wave_sum(p1), s2 = wave_sum(p2);
    if (lane == 0) { sbuf[wv * 3 + 0] = s0; sbuf[wv * 3 + 1] = s1; sbuf[wv * 3 + 2] = s2; }
    __syncthreads();
    float w0 = sbuf[0] + sbuf[3] + sbuf[6] + sbuf[9];
    float w1 = sbuf[1] + sbuf[4] + sbuf[7] + sbuf[10];
    float w2l = sbuf[2] + sbuf[5] + sbuf[8] + sbuf[11];
    float mm = fmaxf(w0, fmaxf(w1, w2l));
    float e0 = __expf(w0 - mm), e1 = __expf(w1 - mm), e2 = __expf(w2l - mm);
    float inv = 1.0f / (e0 + e1 + e2);
    float x = (e0 * inv) * a.sup[idx] + (e1 * inv) * a.psup[idx] + (e2 * inv) * a.nsup[idx];
    a.X[idx] = x;
    atomicAdd(&a.colsum[(n & (NCS - 1)) * KD + d], x);
    __syncthreads();   // protect sbuf across stride iterations
}

// ---------------- final body ----------------
__device__ __forceinline__ void final_body(const MegaArgs& a, int n, char* smem) {
    float* sbuf = (float*)smem;   // [4]
    int d = threadIdx.x;
    float cs = 0.0f;
    #pragma unroll
    for (int r = 0; r < NCS; r++) cs += a.colsum[r * KD + d];
    float mean = cs * (1.0f / KN);
    float xc = a.X[(size_t)n * KD + d] - mean;
    int wv = d >> 6, lane = d & 63;
    float s = wave_sum(xc * xc);
    if (lane == 0) sbuf[wv] = s;
    __syncthreads();
    float ss = sbuf[0] + sbuf[1] + sbuf[2] + sbuf[3];
    a.out[(size_t)n * KD + d] = xc * rsqrtf(1e-6f + ss);
    __syncthreads();   // protect sbuf across stride iterations
}

// ---------------- the mega kernel: 7 phases, 6 soft barriers ----------------
__global__ __launch_bounds__(256, 4) void mega_kernel(MegaArgs a) {
    __shared__ alignas(16) char smem[10368];
    const int nb = NBLK;

    // P0: ycs normalize (512 vbs) + colsum zero (1 vb)
    for (int vb = blockIdx.x; vb < 513; vb += nb) {
        if (vb < 512) {
            int w = threadIdx.x >> 6, lane = threadIdx.x & 63;
            int n = vb * 4 + w;
            float v = a.y[n * KT + lane];
            float mean = wave_sum(v) * (1.0f / KT);
            float yc = v - mean;
            float ss = wave_sum(yc * yc);
            a.ycs[n * KT + lane] = yc * rsqrtf(ss * (1.0f / (KT - 1)));
        } else {
            for (int j = threadIdx.x; j < NCS * KD; j += 256) a.colsum[j] = 0.0f;
        }
    }
    soft_sync(a.bar, 0);

    // P1: corr upper-tri (528 vbs) + 5 emb GEMMs (640 vbs)
    for (int vb = blockIdx.x; vb < 1168; vb += nb) {
        if (vb < 528) {
            corr_body(a.ycs, a.adj, a.cd, vb, smem);
        } else {
            int b = vb - 528;
            int tn = b % 20, tm = b / 20;
            int buf = tn >> 2, coloff = (tn & 3) * 64;
            int h = tn & 3;
            const float* B; const float* bias; float* C;
            float *f1h = nullptr, *f2h = nullptr;
            const float *wu_h = nullptr, *wv_h = nullptr;
            if (buf == 0) {
                B = a.pos_w;  bias = nullptr; C = a.S_pos;
                f1h = a.f1p + h * KN; f2h = a.f2p + h * KN;
                wu_h = a.pos_wu + h * KF; wv_h = a.pos_wv + h * KF;
            } else if (buf == 1) {
                B = a.neg_w;  bias = nullptr; C = a.S_neg;
                f1h = a.f1n + h * KN; f2h = a.f2n + h * KN;
                wu_h = a.neg_wu + h * KF; wv_h = a.neg_wv + h * KF;
            } else if (buf == 2) { B = a.pos_pw; bias = a.pos_pb + coloff; C = a.P_pos; }
            else if (buf == 3)   { B = a.neg_pw; bias = a.neg_pb + coloff; C = a.P_neg; }
            else                 { B = a.self_w; bias = a.self_b + coloff; C = a.sup; }
            mfma_gemm_body<false>(a.emb, KD, tm * 64, B, KD, coloff, bias,
                                  C, KD, coloff, f1h, f2h, wu_h, wv_h, smem);
        }
        __syncthreads();  // smem reuse safety across stride iterations
    }
    soft_sync(a.bar, 1);

    // P2: sparse GAT (2048 vbs)
    for (int vb = blockIdx.x; vb < 2048; vb += nb) {
        attn_body(a, vb, smem);
        __syncthreads();
    }
    soft_sync(a.bar, 2);

    // P3: mlp GEMMs [G_pos;G_neg]->psup|nsup (256 vbs) + T0 (128 vbs)
    for (int vb = blockIdx.x; vb < 384; vb += nb) {
        int bx = vb & 3, by = vb >> 2;
        int cn = bx * 64;
        if (by < 64) {
            int bm = by * 64;
            bool sel = bm >= KN;
            mfma_gemm_body<false>(a.G_pos, KD, bm, sel ? a.mlp_neg_w : a.mlp_pos_w, KD, cn,
                                  (sel ? a.mlp_neg_b : a.mlp_pos_b) + cn, a.psup, KD, cn,
                                  nullptr, nullptr, nullptr, nullptr, smem);
        } else {
            int bm = (by - 64) * 64;
            mfma_gemm_body<true>(a.sup, KD, bm, a.sem_w1, KD, cn,
                                 a.sem_b1 + cn, a.T0, KD, cn,
                                 nullptr, nullptr, nullptr, nullptr, smem);
        }
    }
    soft_sync(a.bar, 3);

    // P4: sem GEMM [psup;nsup] -> [T1;T2] (256 vbs)
    for (int vb = blockIdx.x; vb < 256; vb += nb) {
        int bx = vb & 3, by = vb >> 2;
        int cn = bx * 64;
        mfma_gemm_body<true>(a.psup, KD, by * 64, a.sem_w1, KD, cn,
                             a.sem_b1 + cn, a.T1, KD, cn,
                             nullptr, nullptr, nullptr, nullptr, smem);
    }
    soft_sync(a.bar, 4);

    // P5: semantic blend + colsum (2048 vbs)
    for (int vb = blockIdx.x; vb < 2048; vb += nb) combine_body(a, vb, smem);
    soft_sync(a.bar, 5);

    // P6: PairNorm + store (2048 vbs)
    for (int vb = blockIdx.x; vb < 2048; vb += nb) final_body(a, vb, smem);
}

// ---------------- host ----------------
extern "C" void kernel_launch(void* const* d_in, const int* in_sizes, int n_in,
                              void* d_out, int out_size, void* d_ws, size_t ws_size,
                              hipStream_t stream) {
    typedef const float* fp;
    MegaArgs a;
    a.emb    = (fp)d_in[0];
    a.y      = (fp)d_in[1];
    a.adj    = (fp)d_in[2];
    a.pos_w  = (fp)d_in[3];  a.pos_wu = (fp)d_in[4];  a.pos_wv = (fp)d_in[5];
    a.pos_b  = (fp)d_in[6];  a.pos_pw = (fp)d_in[7];  a.pos_pb = (fp)d_in[8];
    a.neg_w  = (fp)d_in[9];  a.neg_wu = (fp)d_in[10]; a.neg_wv = (fp)d_in[11];
    a.neg_b  = (fp)d_in[12]; a.neg_pw = (fp)d_in[13]; a.neg_pb = (fp)d_in[14];
    a.self_w = (fp)d_in[15]; a.self_b = (fp)d_in[16];
    a.mlp_pos_w = (fp)d_in[17]; a.mlp_pos_b = (fp)d_in[18];
    a.mlp_neg_w = (fp)d_in[19]; a.mlp_neg_b = (fp)d_in[20];
    a.sem_w1 = (fp)d_in[21]; a.sem_b1 = (fp)d_in[22]; a.sem_w2 = (fp)d_in[23];
    a.out = (float*)d_out;

    char* ws = (char*)d_ws;
    a.ycs    = (float*)(ws + 0x0000000);          // 512 KB
    a.cd     = (unsigned char*)(ws + 0x0080000);  // 4 MB
    a.S_pos  = (float*)(ws + 0x0480000);          // 2 MB each
    a.S_neg  = (float*)(ws + 0x0680000);
    a.P_pos  = (float*)(ws + 0x0880000);          // later T0
    a.P_neg  = (float*)(ws + 0x0A80000);          // later T1
    a.G_pos  = (float*)(ws + 0x0C80000);          // later T2 (G_pos|G_neg contiguous)
    a.G_neg  = (float*)(ws + 0x0E80000);          // later X
    a.sup    = (float*)(ws + 0x1080000);          // sup|psup|nsup contiguous
    a.psup   = (float*)(ws + 0x1280000);          // psup|nsup = mlp C stack
    a.nsup   = (float*)(ws + 0x1480000);
    a.colsum = (float*)(ws + 0x1680000);          // 32 KB
    a.f1p    = (float*)(ws + 0x1700000);          // 32 KB each
    a.f2p    = (float*)(ws + 0x1708000);
    a.f1n    = (float*)(ws + 0x1710000);
    a.f2n    = (float*)(ws + 0x1718000);
    a.bar    = (unsigned*)(ws + 0x1720000);       // 64 B barrier counters
    a.T0 = a.P_pos; a.T1 = a.P_neg; a.T2 = a.G_pos; a.X = a.G_neg;

    hipMemsetAsync(a.bar, 0, 64, stream);
    mega_kernel<<<NBLK, 256, 0, stream>>>(a);
}